// Round 1
// baseline (432.431 us; speedup 1.0000x reference)
//
#include <hip/hip_runtime.h>
#include <stdint.h>

#define C_DIM 256
#define L_DIM 8192
#define B_DIM 8
#define CR 64
#define GK 112   // G*K = 16*7
#define GRP 16
#define KW 7
#define PAD 3

using short8  = __attribute__((ext_vector_type(8))) short;
using floatx4 = __attribute__((ext_vector_type(4))) float;

__device__ __forceinline__ unsigned short f2bf(float f) {
    union { float f; uint32_t u; } v; v.f = f;
    uint32_t u = v.u;
    uint32_t r = (u + 0x7fff + ((u >> 16) & 1)) >> 16;
    return (unsigned short)r;
}
__device__ __forceinline__ float bf2f(unsigned short h) {
    union { uint32_t u; float f; } v; v.u = ((uint32_t)h) << 16;
    return v.f;
}

// K0: cast w_main|w_skip (fp32) -> wb bf16, stacked [512][256]
__global__ __launch_bounds__(256) void k0_castw(const float* __restrict__ wm,
                                                const float* __restrict__ wk,
                                                unsigned short* __restrict__ wb) {
    int i = blockIdx.x * 256 + threadIdx.x;   // 0..131071
    float v = (i < 65536) ? wm[i] : wk[i - 65536];
    wb[i] = f2bf(v);
}

// K1: h = relu(w_reduce @ x)  -> hb bf16 (B,64,L).  16 rows per thread.
__global__ __launch_bounds__(256) void k1_reduce(const float* __restrict__ x,
                                                 const float* __restrict__ wr,
                                                 unsigned short* __restrict__ hb) {
    int bid = blockIdx.x;
    int rg = bid & 3;            // row-group fastest -> L2 reuse of x slice
    int lb = (bid >> 2) & 31;
    int b  = bid >> 7;
    int l  = lb * 256 + threadIdx.x;
    int r0 = rg * 16;
    const float* xp = x + (size_t)b * C_DIM * L_DIM + l;
    float acc[16];
#pragma unroll
    for (int i = 0; i < 16; ++i) acc[i] = 0.f;
#pragma unroll 4
    for (int cc = 0; cc < C_DIM; ++cc) {
        float xv = xp[(size_t)cc * L_DIM];
#pragma unroll
        for (int i = 0; i < 16; ++i)
            acc[i] = fmaf(wr[(r0 + i) * C_DIM + cc], xv, acc[i]);
    }
#pragma unroll
    for (int i = 0; i < 16; ++i) {
        float v = acc[i] > 0.f ? acc[i] : 0.f;
        hb[((size_t)b * CR + r0 + i) * L_DIM + l] = f2bf(v);
    }
}

// K2: ker = w_span @ h  -> kb bf16 (B,112,L). 16 rows per thread.
__global__ __launch_bounds__(256) void k2_span(const unsigned short* __restrict__ hb,
                                               const float* __restrict__ wsp,
                                               unsigned short* __restrict__ kb) {
    int bid = blockIdx.x;
    int rg = bid % 7;
    int lb = (bid / 7) & 31;
    int b  = bid / 224;
    int l  = lb * 256 + threadIdx.x;
    int r0 = rg * 16;
    const unsigned short* hp = hb + (size_t)b * CR * L_DIM + l;
    float acc[16];
#pragma unroll
    for (int i = 0; i < 16; ++i) acc[i] = 0.f;
#pragma unroll 4
    for (int cc = 0; cc < CR; ++cc) {
        float hv = bf2f(hp[(size_t)cc * L_DIM]);
#pragma unroll
        for (int i = 0; i < 16; ++i)
            acc[i] = fmaf(wsp[(r0 + i) * CR + cc], hv, acc[i]);
    }
#pragma unroll
    for (int i = 0; i < 16; ++i)
        kb[((size_t)b * GK + r0 + i) * L_DIM + l] = f2bf(acc[i]);
}

// K3: involution + PReLU + LayerNorm(C). One block = (b, 32 columns).
// Writes normalized activations TRANSPOSED bf16: xnt[(b*L + l)*256 + c]
#define TL 32
__global__ __launch_bounds__(256) void k3_inv_ln(const float* __restrict__ x,
                                                 const unsigned short* __restrict__ kb,
                                                 const float* __restrict__ pa,
                                                 const float* __restrict__ gamma,
                                                 const float* __restrict__ beta,
                                                 unsigned short* __restrict__ xnt) {
    __shared__ float xs[256 * 39];      // [c][jj], jj in [0,38), stride 39 (odd -> no conflicts)
    __shared__ float ks[GK * TL];       // [gk][j]
    __shared__ float red1[256], red2[256];
    __shared__ float mean_s[TL], rstd_s[TL];

    int bid = blockIdx.x;
    int b  = bid >> 8;                  // 256 l-blocks per batch
    int l0 = (bid & 255) * TL;
    int t  = threadIdx.x;

    // stage x tile with halo (zero pad at batch edges), coalesced along l
    for (int i = t; i < 256 * 38; i += 256) {
        int c = i / 38, jj = i - c * 38;
        int l = l0 + jj - PAD;
        xs[c * 39 + jj] = (l >= 0 && l < L_DIM) ? x[((size_t)b * C_DIM + c) * L_DIM + l] : 0.f;
    }
    // stage ker tile (bf16 -> f32)
    for (int i = t; i < GK * TL; i += 256) {
        int r = i >> 5, j = i & 31;
        ks[r * TL + j] = bf2f(kb[((size_t)b * GK + r) * L_DIM + l0 + j]);
    }
    __syncthreads();

    int c = t, g = c >> 4;
    float xwin[38];
#pragma unroll
    for (int jj = 0; jj < 38; ++jj) xwin[jj] = xs[c * 39 + jj];

    float acc[TL];
#pragma unroll
    for (int j = 0; j < TL; ++j) acc[j] = 0.f;
#pragma unroll
    for (int k = 0; k < KW; ++k) {
        const float4* kr = (const float4*)&ks[(g * KW + k) * TL];
#pragma unroll
        for (int jc = 0; jc < 8; ++jc) {
            float4 kv = kr[jc];
            acc[jc * 4 + 0] = fmaf(kv.x, xwin[jc * 4 + 0 + k], acc[jc * 4 + 0]);
            acc[jc * 4 + 1] = fmaf(kv.y, xwin[jc * 4 + 1 + k], acc[jc * 4 + 1]);
            acc[jc * 4 + 2] = fmaf(kv.z, xwin[jc * 4 + 2 + k], acc[jc * 4 + 2]);
            acc[jc * 4 + 3] = fmaf(kv.w, xwin[jc * 4 + 3 + k], acc[jc * 4 + 3]);
        }
    }
    // PReLU
    float a = pa[0];
#pragma unroll
    for (int j = 0; j < TL; ++j) acc[j] = acc[j] >= 0.f ? acc[j] : a * acc[j];

    __syncthreads();                    // all xwin reads done; reuse xs region
    float* outs = xs;                   // [256][33]
#pragma unroll
    for (int j = 0; j < TL; ++j) outs[c * 33 + j] = acc[j];
    __syncthreads();

    // per-column mean/var over 256 channels
    int j = t & 31, cg = t >> 5;
    float s1 = 0.f, s2 = 0.f;
#pragma unroll 8
    for (int i = 0; i < 32; ++i) {
        float v = outs[(cg * 32 + i) * 33 + j];
        s1 += v; s2 += v * v;
    }
    red1[cg * 32 + j] = s1; red2[cg * 32 + j] = s2;
    __syncthreads();
    if (t < 32) {
        float t1 = 0.f, t2 = 0.f;
#pragma unroll
        for (int i = 0; i < 8; ++i) { t1 += red1[i * 32 + t]; t2 += red2[i * 32 + t]; }
        float mu  = t1 * (1.f / 256.f);
        float var = t2 * (1.f / 256.f) - mu * mu;
        mean_s[t] = mu;
        rstd_s[t] = rsqrtf(var + 1e-5f);
    }
    __syncthreads();

    float gam = gamma[c], bet = beta[c];
#pragma unroll
    for (int j2 = 0; j2 < TL; ++j2) {
        float v = (acc[j2] - mean_s[j2]) * rstd_s[j2] * gam + bet;
        xnt[((size_t)b * L_DIM + l0 + j2) * C_DIM + c] = f2bf(v);
    }
}

// K4: [main;skip] = Wcat(512x256) @ outn(256x65536), +x residual on main rows.
// MFMA f32_16x16x32_bf16. Block = 64(M) x 64(N), K=256 fully staged in LDS.
#define LDR 264   // row stride in shorts: 256 + 8 pad (528B = 33*16B, keeps 16B align)
__global__ __launch_bounds__(256) void k4_gemm(const unsigned short* __restrict__ wb,
                                               const unsigned short* __restrict__ xnt,
                                               const float* __restrict__ x,
                                               float* __restrict__ out) {
    __shared__ unsigned short As[64 * LDR];
    __shared__ unsigned short Xs[64 * LDR];
    int bid = blockIdx.x;
    int mb = bid & 7;                  // M-block fastest -> xnt tile L2 reuse
    int nb = bid >> 3;
    int t = threadIdx.x;

    const uint4* wsrc = (const uint4*)(wb + (size_t)mb * 64 * C_DIM);
    const uint4* xsrc = (const uint4*)(xnt + (size_t)nb * 64 * C_DIM);
#pragma unroll
    for (int i = 0; i < 8; ++i) {
        int cid = t + i * 256;         // 2048 16B chunks per tile
        int row = cid >> 5, kc = cid & 31;
        *(uint4*)&As[row * LDR + kc * 8] = wsrc[cid];
        *(uint4*)&Xs[row * LDR + kc * 8] = xsrc[cid];
    }
    __syncthreads();

    int w = t >> 6, lane = t & 63;
    int lr = lane & 15, quad = lane >> 4;

    short8 af[8];
#pragma unroll
    for (int s = 0; s < 8; ++s)
        af[s] = *(const short8*)&As[(w * 16 + lr) * LDR + s * 32 + quad * 8];

    floatx4 acc[4];
#pragma unroll
    for (int t4 = 0; t4 < 4; ++t4) {
        acc[t4] = (floatx4){0.f, 0.f, 0.f, 0.f};
#pragma unroll
        for (int s = 0; s < 8; ++s) {
            short8 bf = *(const short8*)&Xs[(t4 * 16 + lr) * LDR + s * 32 + quad * 8];
            acc[t4] = __builtin_amdgcn_mfma_f32_16x16x32_bf16(af[s], bf, acc[t4], 0, 0, 0);
        }
    }

    int col0 = nb * 64;
#pragma unroll
    for (int t4 = 0; t4 < 4; ++t4) {
#pragma unroll
        for (int r = 0; r < 4; ++r) {
            int m   = mb * 64 + w * 16 + quad * 4 + r;   // D row = quad*4+reg
            int col = col0 + t4 * 16 + lr;               // D col = lane&15
            int b = col >> 13, l = col & 8191;
            float v = acc[t4][r];
            if (m < C_DIM) {
                size_t idx = ((size_t)b * C_DIM + m) * L_DIM + l;
                out[idx] = v + x[idx];
            } else {
                size_t idx = ((size_t)b * C_DIM + (m - C_DIM)) * L_DIM + l;
                out[(size_t)B_DIM * C_DIM * L_DIM + idx] = v;
            }
        }
    }
}

extern "C" void kernel_launch(void* const* d_in, const int* in_sizes, int n_in,
                              void* d_out, int out_size, void* d_ws, size_t ws_size,
                              hipStream_t stream) {
    const float* x     = (const float*)d_in[0];
    const float* w_red = (const float*)d_in[1];
    const float* w_spn = (const float*)d_in[2];
    const float* pa    = (const float*)d_in[3];
    const float* gam   = (const float*)d_in[4];
    const float* bet   = (const float*)d_in[5];
    const float* w_m   = (const float*)d_in[6];
    const float* w_s   = (const float*)d_in[7];
    float* out = (float*)d_out;

    // workspace layout (bytes)
    char* ws = (char*)d_ws;
    unsigned short* wb  = (unsigned short*)(ws);                         // 512*256*2   = 262144
    unsigned short* hb  = (unsigned short*)(ws + 262144);                // 8*64*8192*2 = 8388608
    unsigned short* kb  = (unsigned short*)(ws + 262144 + 8388608);      // 8*112*8192*2= 14680064
    unsigned short* xnt = (unsigned short*)(ws + 262144 + 8388608 + 14680064); // 8*8192*256*2 = 33554432

    k0_castw<<<512, 256, 0, stream>>>(w_m, w_s, wb);
    k1_reduce<<<1024, 256, 0, stream>>>(x, w_red, hb);
    k2_span<<<1792, 256, 0, stream>>>(hb, w_spn, kb);
    k3_inv_ln<<<2048, 256, 0, stream>>>(x, kb, pa, gam, bet, xnt);
    k4_gemm<<<8192, 256, 0, stream>>>(wb, xnt, x, out);
}